// Round 5
// baseline (426.498 us; speedup 1.0000x reference)
//
#include <hip/hip_runtime.h>

#define EPS 1e-5f
constexpr int HD = 128;   // node feature / hidden dim
constexpr int FCD = 64;   // fc hidden dim

typedef __attribute__((ext_vector_type(8))) short short8;
typedef __attribute__((ext_vector_type(4))) float floatx4;

// ---------- bf16 helpers ----------
__device__ inline ushort f2bf(float f){
  union{float f; unsigned u;} v; v.f = f;
  unsigned r = v.u + 0x7FFFu + ((v.u >> 16) & 1u);
  return (ushort)(r >> 16);
}
__device__ inline float bflo(unsigned u){ union{unsigned i; float f;} v; v.i = u << 16;        return v.f; }
__device__ inline float bfhi(unsigned u){ union{unsigned i; float f;} v; v.i = u & 0xFFFF0000u; return v.f; }
__device__ inline float bf2f(ushort u){ union{unsigned i; float f;} v; v.i = ((unsigned)u) << 16; return v.f; }

// ------------------- preprocessing -------------------

__global__ void k_count(const int* __restrict__ dst, int* __restrict__ cnt, int E){
  int e = blockIdx.x*256 + threadIdx.x;
  if (e < E) atomicAdd(&cnt[dst[e]], 1);
}

// chunk = 1024 elements (256 thr x int4). nChunks <= 64 assumed (N <= 65536).
__global__ __launch_bounds__(256) void k_chunksum(const int* __restrict__ cnt,
                                                  int* __restrict__ csum, int n){
  __shared__ int ws[4];
  int idx = blockIdx.x*1024 + threadIdx.x*4;
  int4 v = make_int4(0,0,0,0);
  if (idx + 3 < n) v = *(const int4*)&cnt[idx];
  else {
    if (idx   < n) v.x = cnt[idx];
    if (idx+1 < n) v.y = cnt[idx+1];
    if (idx+2 < n) v.z = cnt[idx+2];
  }
  int s = v.x + v.y + v.z + v.w;
  #pragma unroll
  for (int o = 1; o < 64; o <<= 1) s += __shfl_xor(s, o, 64);
  int lane = threadIdx.x & 63, wave = threadIdx.x >> 6;
  if (lane == 0) ws[wave] = s;
  __syncthreads();
  if (threadIdx.x == 0) csum[blockIdx.x] = ws[0]+ws[1]+ws[2]+ws[3];
}

__global__ __launch_bounds__(256) void k_scan2(const int* __restrict__ cnt,
                                               const int* __restrict__ csum,
                                               int* __restrict__ rowptr,
                                               int* __restrict__ cursor,
                                               float* __restrict__ dis, int n){
  __shared__ int sOff;
  __shared__ int wtot[4];
  int chunk = blockIdx.x;
  int tid = threadIdx.x, lane = tid & 63, wave = tid >> 6;
  if (wave == 0){
    int v = (lane < chunk) ? csum[lane] : 0;
    #pragma unroll
    for (int o = 1; o < 64; o <<= 1) v += __shfl_xor(v, o, 64);
    if (lane == 0) sOff = v;
  }
  int idx = chunk*1024 + tid*4;
  int4 v = make_int4(0,0,0,0);
  if (idx + 3 < n) v = *(const int4*)&cnt[idx];
  else {
    if (idx   < n) v.x = cnt[idx];
    if (idx+1 < n) v.y = cnt[idx+1];
    if (idx+2 < n) v.z = cnt[idx+2];
  }
  int s = v.x + v.y + v.z + v.w;
  int incl = s;
  #pragma unroll
  for (int o = 1; o < 64; o <<= 1){
    int t = __shfl_up(incl, o, 64);
    if (lane >= o) incl += t;
  }
  if (lane == 63) wtot[wave] = incl;
  __syncthreads();
  int woff = 0;
  for (int w = 0; w < wave; ++w) woff += wtot[w];
  int pre = sOff + woff + (incl - s);
  if (idx < n){
    if (idx == 0) rowptr[0] = 0;
    cursor[idx] = pre; rowptr[idx+1] = pre + v.x; dis[idx] = rsqrtf((float)v.x + 1.0f);
    pre += v.x;
    if (idx+1 < n){
      cursor[idx+1] = pre; rowptr[idx+2] = pre + v.y; dis[idx+1] = rsqrtf((float)v.y + 1.0f);
      pre += v.y;
      if (idx+2 < n){
        cursor[idx+2] = pre; rowptr[idx+3] = pre + v.z; dis[idx+2] = rsqrtf((float)v.z + 1.0f);
        pre += v.z;
        if (idx+3 < n){
          cursor[idx+3] = pre; rowptr[idx+4] = pre + v.w; dis[idx+3] = rsqrtf((float)v.w + 1.0f);
        }
      }
    }
  }
}

// weights factorized out: edata stores src index only (4B scatter, nontemporal)
__global__ void k_fill(const int* __restrict__ src, const int* __restrict__ dst,
                       int* __restrict__ cursor, int* __restrict__ csrc, int E){
  int e = blockIdx.x*256 + threadIdx.x;
  if (e >= E) return;
  int s = src[e], d = dst[e];
  int pos = atomicAdd(&cursor[d], 1);
  __builtin_nontemporal_store(s, &csrc[pos]);
}

// pack W [128,128] fp32 -> fragment-major bf16 for mfma_f32_16x16x32_bf16 B-operand
__global__ void k_prepW(const float* __restrict__ W1, const float* __restrict__ W2,
                        const float* __restrict__ W3, ushort* __restrict__ Wf){
  const float* Ws[3] = {W1, W2, W3};
  int l = blockIdx.y;
  int idx = blockIdx.x*256 + threadIdx.x;        // 0..16383
  int k = idx >> 7, n = idx & 127;
  float w = Ws[l][idx];
  int kb = k >> 5, q = (k >> 3) & 3, j = k & 7;
  int nt = n >> 4, col = n & 15;
  Wf[(size_t)l*16384 + (((size_t)(kb*8 + nt)*64 + q*16 + col)*8 + j)] = f2bf(w);
}

// ------------------- GEMM: bf16 MFMA, fused BN-affine+ReLU on A, dis-scale on out ----
// MODE 0: A fp32 (= x), plain convert. MODE 1: A bf16 (= AGG), affine+relu in fp32.
// Output rows scaled by dis[row] (GCN weight factorization).
template<int MODE>
__global__ __launch_bounds__(256) void k_gemm(const void* __restrict__ Av,
                                              const ushort* __restrict__ Wf,
                                              const float* __restrict__ sums,
                                              const float* __restrict__ g,
                                              const float* __restrict__ be,
                                              const float* __restrict__ dis,
                                              ushort* __restrict__ O, int n, float invN){
  __shared__ float aL[HD], bL[HD];
  int tid = threadIdx.x;
  if (MODE){
    if (tid < HD){
      float m = sums[tid]*invN;
      float var = fmaxf(sums[HD+tid]*invN - m*m, 0.f);
      float Ac = g[tid]*rsqrtf(var + EPS);
      aL[tid] = Ac; bL[tid] = be[tid] - m*Ac;
    }
    __syncthreads();
  }
  int lane = tid & 63, wave = tid >> 6;
  int quad = lane >> 4, r16 = lane & 15;
  int row = blockIdx.x*64 + wave*16 + r16;
  int rowc = min(row, n-1);
  floatx4 acc[8] = {};
  #pragma unroll
  for (int kb = 0; kb < 4; ++kb){
    int k0 = kb*32 + quad*8;
    short8 af;
    if (MODE){
      const ushort* Arow = (const ushort*)Av + (size_t)rowc*HD;
      short8 raw = *(const short8*)(Arow + k0);
      #pragma unroll
      for (int jj = 0; jj < 8; ++jj){
        float f = bf2f((ushort)raw[jj]);
        f = fmaxf(f*aL[k0+jj] + bL[k0+jj], 0.f);
        af[jj] = (short)f2bf(f);
      }
    } else {
      const float* Arow = (const float*)Av + (size_t)rowc*HD;
      float4 x0 = *(const float4*)(Arow + k0);
      float4 x1 = *(const float4*)(Arow + k0 + 4);
      af[0] = (short)f2bf(x0.x); af[1] = (short)f2bf(x0.y);
      af[2] = (short)f2bf(x0.z); af[3] = (short)f2bf(x0.w);
      af[4] = (short)f2bf(x1.x); af[5] = (short)f2bf(x1.y);
      af[6] = (short)f2bf(x1.z); af[7] = (short)f2bf(x1.w);
    }
    const ushort* wp = Wf + ((size_t)(kb*8)*64 + lane)*8;
    #pragma unroll
    for (int nt = 0; nt < 8; ++nt){
      short8 bf = *(const short8*)(wp + (size_t)nt*64*8);
      acc[nt] = __builtin_amdgcn_mfma_f32_16x16x32_bf16(af, bf, acc[nt], 0, 0, 0);
    }
  }
  int rbase = blockIdx.x*64 + wave*16 + quad*4;
  float ds[4];
  #pragma unroll
  for (int r = 0; r < 4; ++r) ds[r] = dis[min(rbase + r, n-1)];
  #pragma unroll
  for (int nt = 0; nt < 8; ++nt){
    #pragma unroll
    for (int r = 0; r < 4; ++r){
      int rr = rbase + r;
      if (rr < n) O[(size_t)rr*HD + nt*16 + r16] = f2bf(acc[nt][r]*ds[r]);
    }
  }
}

// ------------------- edge aggregation + fused BN-stats partials -------------------
// 16 lanes/node, 16 nodes/block; weightless edges; 8-edge unroll with prefetch;
// AGG[i] = dis[i]*(hws[i] + sum hws[src]); stats from fp32, bf16 output.
__global__ __launch_bounds__(256) void k_gather(const ushort* __restrict__ hw,
                                                const int* __restrict__ rowptr,
                                                const int* __restrict__ csrc,
                                                const float* __restrict__ dis,
                                                ushort* __restrict__ agg,
                                                float* __restrict__ scratch,
                                                float* __restrict__ sums, int N){
  __shared__ float2 sm[4][HD];
  if (blockIdx.x == 0) sums[threadIdx.x] = 0.f;   // zero before k_reduce's atomics
  int grp = threadIdx.x >> 4, j = threadIdx.x & 15;
  int wave = threadIdx.x >> 6, lane = threadIdx.x & 63;
  int i = blockIdx.x*16 + grp;
  bool valid = (i < N);
  int ic = valid ? i : N-1;
  uint4 q = ((const uint4*)(hw + (size_t)ic*HD))[j];
  float a[8];
  a[0] = bflo(q.x); a[1] = bfhi(q.x);
  a[2] = bflo(q.y); a[3] = bfhi(q.y);
  a[4] = bflo(q.z); a[5] = bfhi(q.z);
  a[6] = bflo(q.w); a[7] = bfhi(q.w);
  int e = rowptr[ic], e1 = rowptr[ic+1];
  #define ADD8(Q) \
    a[0] += bflo(Q.x); a[1] += bfhi(Q.x); \
    a[2] += bflo(Q.y); a[3] += bfhi(Q.y); \
    a[4] += bflo(Q.z); a[5] += bfhi(Q.z); \
    a[6] += bflo(Q.w); a[7] += bfhi(Q.w);
  // align e to 4 for int4 loads
  while (e < e1 && (e & 3)){
    uint4 qq = ((const uint4*)(hw + (size_t)csrc[e]*HD))[j];
    ADD8(qq);
    e++;
  }
  int4 c0, c1;
  if (e + 8 <= e1){
    c0 = *(const int4*)&csrc[e];
    c1 = *(const int4*)&csrc[e+4];
  }
  while (e + 8 <= e1){
    int en = e + 8;
    int4 n0, n1;
    if (en + 8 <= e1){                     // prefetch next 8 edge indices
      n0 = *(const int4*)&csrc[en];
      n1 = *(const int4*)&csrc[en+4];
    }
    uint4 q0 = ((const uint4*)(hw + (size_t)c0.x*HD))[j];
    uint4 q1 = ((const uint4*)(hw + (size_t)c0.y*HD))[j];
    uint4 q2 = ((const uint4*)(hw + (size_t)c0.z*HD))[j];
    uint4 q3 = ((const uint4*)(hw + (size_t)c0.w*HD))[j];
    uint4 q4 = ((const uint4*)(hw + (size_t)c1.x*HD))[j];
    uint4 q5 = ((const uint4*)(hw + (size_t)c1.y*HD))[j];
    uint4 q6 = ((const uint4*)(hw + (size_t)c1.z*HD))[j];
    uint4 q7 = ((const uint4*)(hw + (size_t)c1.w*HD))[j];
    ADD8(q0); ADD8(q1); ADD8(q2); ADD8(q3);
    ADD8(q4); ADD8(q5); ADD8(q6); ADD8(q7);
    c0 = n0; c1 = n1; e = en;
  }
  if (e + 4 <= e1){
    int4 t = *(const int4*)&csrc[e];
    uint4 q0 = ((const uint4*)(hw + (size_t)t.x*HD))[j];
    uint4 q1 = ((const uint4*)(hw + (size_t)t.y*HD))[j];
    uint4 q2 = ((const uint4*)(hw + (size_t)t.z*HD))[j];
    uint4 q3 = ((const uint4*)(hw + (size_t)t.w*HD))[j];
    ADD8(q0); ADD8(q1); ADD8(q2); ADD8(q3);
    e += 4;
  }
  for (; e < e1; ++e){
    uint4 qq = ((const uint4*)(hw + (size_t)csrc[e]*HD))[j];
    ADD8(qq);
  }
  #undef ADD8
  float sc = dis[ic];
  #pragma unroll
  for (int k = 0; k < 8; ++k) a[k] *= sc;
  if (valid){
    uint4 o;
    o.x = (unsigned)f2bf(a[0]) | ((unsigned)f2bf(a[1]) << 16);
    o.y = (unsigned)f2bf(a[2]) | ((unsigned)f2bf(a[3]) << 16);
    o.z = (unsigned)f2bf(a[4]) | ((unsigned)f2bf(a[5]) << 16);
    o.w = (unsigned)f2bf(a[6]) | ((unsigned)f2bf(a[7]) << 16);
    ((uint4*)(agg + (size_t)i*HD))[j] = o;
  }
  // fused stats
  float z = valid ? 1.f : 0.f;
  #pragma unroll
  for (int k = 0; k < 8; ++k){
    float s = a[k]*z, qq = a[k]*a[k]*z;
    s  += __shfl_xor(s, 16);  s  += __shfl_xor(s, 32);
    qq += __shfl_xor(qq, 16); qq += __shfl_xor(qq, 32);
    if (lane < 16) sm[wave][lane*8 + k] = make_float2(s, qq);
  }
  __syncthreads();
  int t = threadIdx.x;
  if (t < HD){
    float2 r0 = sm[0][t], r1 = sm[1][t], r2 = sm[2][t], r3 = sm[3][t];
    scratch[(size_t)blockIdx.x*256 + t]      = r0.x + r1.x + r2.x + r3.x;
    scratch[(size_t)blockIdx.x*256 + HD + t] = r0.y + r1.y + r2.y + r3.y;
  }
}

// coalesced second-stage reduction
__global__ __launch_bounds__(256) void k_reduce(const float* __restrict__ scratch,
                                                float* __restrict__ sums, int R){
  int t = threadIdx.x;
  float acc = 0.f;
  for (int r = blockIdx.x; r < R; r += gridDim.x)
    acc += scratch[(size_t)r*256 + t];
  atomicAdd(&sums[t], acc);
}

// ------------------- mean pool (fused layer-3 BN+ReLU, fused counts) -------------------

__global__ __launch_bounds__(128) void k_pool(const ushort* __restrict__ h,
                                              const int* __restrict__ batch,
                                              const float* __restrict__ sums,
                                              const float* __restrict__ g,
                                              const float* __restrict__ be,
                                              float* __restrict__ pooled,
                                              float* __restrict__ cntf, int N, float invN){
  int c = threadIdx.x;
  float m = sums[c]*invN;
  float var = fmaxf(sums[HD+c]*invN - m*m, 0.f);
  float a = g[c]*rsqrtf(var + EPS);
  float b = be[c] - m*a;
  int start = blockIdx.x * 32;
  if (start >= N) return;
  int end = min(start + 32, N);
  int cur = batch[start];
  float acc = 0.f; int run = 0;
  for (int i = start; i < end; ++i){
    int bb = batch[i];
    if (bb != cur){
      atomicAdd(&pooled[(size_t)cur*HD + c], acc);
      if (c == 0) atomicAdd(&cntf[cur], (float)run);
      acc = 0.f; run = 0; cur = bb;
    }
    acc += fmaxf(bf2f(h[(size_t)i*HD + c])*a + b, 0.f);
    run++;
  }
  atomicAdd(&pooled[(size_t)cur*HD + c], acc);
  if (c == 0) atomicAdd(&cntf[cur], (float)run);
}

// ------------------- FC head -------------------

__global__ __launch_bounds__(64) void k_fc1(const float* __restrict__ pooled,
                                            const float* __restrict__ cntf,
                                            const float* __restrict__ W,
                                            const float* __restrict__ b,
                                            float* __restrict__ z,
                                            float* __restrict__ sums2, int G){
  int g = blockIdx.x, j = threadIdx.x;
  if (g == 0){ sums2[j] = 0.f; sums2[FCD + j] = 0.f; }
  float inv = 1.0f / fmaxf(cntf[g], 1.0f);
  float acc = 0.f;
  for (int k = 0; k < HD; ++k)
    acc += pooled[(size_t)g*HD + k] * W[k*FCD + j];
  z[(size_t)g*FCD + j] = acc * inv + b[j];
}

__global__ __launch_bounds__(64) void k_stats2(const float* __restrict__ z,
                                               float* __restrict__ sums2, int G){
  int c = threadIdx.x;
  float s = 0.f, q = 0.f;
  for (int i = blockIdx.x; i < G; i += gridDim.x){
    float v = z[(size_t)i*FCD + c]; s += v; q += v*v;
  }
  atomicAdd(&sums2[c], s);
  atomicAdd(&sums2[FCD + c], q);
}

__global__ __launch_bounds__(64) void k_final(const float* __restrict__ z,
                                              const float* __restrict__ sums2,
                                              const float* __restrict__ g,
                                              const float* __restrict__ be,
                                              const float* __restrict__ w2,
                                              const float* __restrict__ b2,
                                              float* __restrict__ out, int G, float invG){
  int gg = blockIdx.x, c = threadIdx.x;
  float m = sums2[c]*invG;
  float var = fmaxf(sums2[FCD+c]*invG - m*m, 0.f);
  float A = g[c]*rsqrtf(var + EPS);
  float B = be[c] - m*A;
  float v = fmaxf(z[(size_t)gg*FCD + c]*A + B, 0.f) * w2[c];
  #pragma unroll
  for (int o = 32; o > 0; o >>= 1) v += __shfl_down(v, o, 64);
  if (c == 0) out[gg] = v + b2[0];
}

// ------------------- launch -------------------

extern "C" void kernel_launch(void* const* d_in, const int* in_sizes, int n_in,
                              void* d_out, int out_size, void* d_ws, size_t ws_size,
                              hipStream_t stream){
  const float* x    = (const float*)d_in[0];
  const int*   ei   = (const int*)d_in[1];
  const int*   batch= (const int*)d_in[2];
  const float* W1 = (const float*)d_in[3];
  const float* g1 = (const float*)d_in[5];
  const float* be1= (const float*)d_in[6];
  const float* W2 = (const float*)d_in[7];
  const float* g2 = (const float*)d_in[9];
  const float* be2= (const float*)d_in[10];
  const float* W3 = (const float*)d_in[11];
  const float* g3 = (const float*)d_in[13];
  const float* be3= (const float*)d_in[14];
  const float* fcW1 = (const float*)d_in[15];
  const float* fcb1 = (const float*)d_in[16];
  const float* fcg1 = (const float*)d_in[17];
  const float* fcbe1= (const float*)d_in[18];
  const float* fcW2 = (const float*)d_in[19];
  const float* fcb2 = (const float*)d_in[20];
  float* out = (float*)d_out;

  const int N = in_sizes[0] / HD;      // 50000
  const int E = in_sizes[1] / 2;       // 800000
  const int G = out_size;              // 500

  const int* esrc = ei;
  const int* edst = ei + E;

  char* p = (char*)d_ws;
  auto alloc = [&](size_t bytes)->void*{
    void* r = (void*)p; p += (bytes + 255) & ~(size_t)255; return r;
  };
  int gatherBlocks = (N + 15)/16;
  int nChunks = (N + 1023)/1024;       // 49 (<= 64 required by k_scan2)
  int*    cnt    = (int*)   alloc((size_t)N*4);
  int*    rowptr = (int*)   alloc((size_t)(N+1)*4);
  int*    cursor = (int*)   alloc((size_t)N*4);
  int*    csum   = (int*)   alloc((size_t)nChunks*4);
  int*    csrc   = (int*)   alloc((size_t)E*4);
  float*  dis    = (float*) alloc((size_t)N*4);
  ushort* HWb    = (ushort*)alloc((size_t)N*HD*2);
  ushort* AGG    = (ushort*)alloc((size_t)N*HD*2);
  ushort* Wf     = (ushort*)alloc((size_t)3*HD*HD*2);
  float*  sums   = (float*) alloc(2*HD*4);
  float*  scratch= (float*) alloc((size_t)gatherBlocks*256*4);
  float*  pooled = (float*) alloc(((size_t)G*HD + G)*4);
  float*  cntf   = pooled + (size_t)G*HD;
  float*  zbuf   = (float*) alloc((size_t)G*FCD*4);
  float*  sums2  = (float*) alloc(2*FCD*4);

  int eb = (E + 255)/256;
  float invN = 1.0f/(float)N, invG = 1.0f/(float)G;

  // preprocessing
  hipMemsetAsync(cnt, 0, (size_t)N*4, stream);
  k_count   <<<eb, 256, 0, stream>>>(edst, cnt, E);
  k_chunksum<<<nChunks, 256, 0, stream>>>(cnt, csum, N);
  k_scan2   <<<nChunks, 256, 0, stream>>>(cnt, csum, rowptr, cursor, dis, N);
  k_fill    <<<eb, 256, 0, stream>>>(esrc, edst, cursor, csrc, E);
  k_prepW   <<<dim3(64,3), 256, 0, stream>>>(W1, W2, W3, Wf);

  int gemmBlocks = (N + 63)/64;

  // layer 1
  k_gemm<0> <<<gemmBlocks, 256, 0, stream>>>(x,   Wf,         nullptr, nullptr, nullptr, dis, HWb, N, invN);
  k_gather  <<<gatherBlocks, 256, 0, stream>>>(HWb, rowptr, csrc, dis, AGG, scratch, sums, N);
  k_reduce  <<<64, 256, 0, stream>>>(scratch, sums, gatherBlocks);
  // layer 2 (BN1+ReLU fused into A-load)
  k_gemm<1> <<<gemmBlocks, 256, 0, stream>>>(AGG, Wf + 16384, sums, g1, be1, dis, HWb, N, invN);
  k_gather  <<<gatherBlocks, 256, 0, stream>>>(HWb, rowptr, csrc, dis, AGG, scratch, sums, N);
  k_reduce  <<<64, 256, 0, stream>>>(scratch, sums, gatherBlocks);
  // layer 3 (BN2+ReLU fused into A-load)
  k_gemm<1> <<<gemmBlocks, 256, 0, stream>>>(AGG, Wf + 32768, sums, g2, be2, dis, HWb, N, invN);
  k_gather  <<<gatherBlocks, 256, 0, stream>>>(HWb, rowptr, csrc, dis, AGG, scratch, sums, N);
  k_reduce  <<<64, 256, 0, stream>>>(scratch, sums, gatherBlocks);

  // pool (BN3+ReLU fused) + head
  hipMemsetAsync(pooled, 0, ((size_t)G*HD + G)*4, stream);
  k_pool  <<<(N+31)/32, 128, 0, stream>>>(AGG, batch, sums, g3, be3, pooled, cntf, N, invN);
  k_fc1   <<<G, FCD, 0, stream>>>(pooled, cntf, fcW1, fcb1, zbuf, sums2, G);
  k_stats2<<<64, FCD, 0, stream>>>(zbuf, sums2, G);
  k_final <<<G, FCD, 0, stream>>>(zbuf, sums2, fcg1, fcbe1, fcW2, fcb2, out, G, invG);
}

// Round 6
// 359.161 us; speedup vs baseline: 1.1875x; 1.1875x over previous
//
#include <hip/hip_runtime.h>

#define EPS 1e-5f
constexpr int HD = 128;   // node feature / hidden dim
constexpr int FCD = 64;   // fc hidden dim

typedef __attribute__((ext_vector_type(8))) short short8;
typedef __attribute__((ext_vector_type(4))) float floatx4;

// ---------- bf16 helpers ----------
__device__ inline ushort f2bf(float f){
  union{float f; unsigned u;} v; v.f = f;
  unsigned r = v.u + 0x7FFFu + ((v.u >> 16) & 1u);
  return (ushort)(r >> 16);
}
__device__ inline float bflo(unsigned u){ union{unsigned i; float f;} v; v.i = u << 16;        return v.f; }
__device__ inline float bfhi(unsigned u){ union{unsigned i; float f;} v; v.i = u & 0xFFFF0000u; return v.f; }
__device__ inline float bf2f(ushort u){ union{unsigned i; float f;} v; v.i = ((unsigned)u) << 16; return v.f; }

// ================= CSR build: 2-level bucket sort =================
// Level 1: bucket edges by dst>>8 (<=256 buckets). Level 2: one block per
// bucket groups by exact dst, emitting rowptr/dis/csrc. All global writes
// are LDS-staged and (mostly) coalesced — no random 4B scatter to HBM.

// per-block LDS histogram of dst>>8, one global atomic per bucket per block
__global__ __launch_bounds__(256) void k_hist(const int* __restrict__ dst,
                                              int* __restrict__ bucketHist, int E){
  __shared__ int h[256];
  int t = threadIdx.x;
  h[t] = 0;
  __syncthreads();
  int base = blockIdx.x*4096;
  #pragma unroll
  for (int k = 0; k < 16; ++k){
    int e = base + k*256 + t;
    if (e < E) atomicAdd(&h[dst[e] >> 8], 1);
  }
  __syncthreads();
  if (h[t]) atomicAdd(&bucketHist[t], h[t]);
}

// 1 block: exclusive scan of 256 bucket counts -> base & cursor
__global__ __launch_bounds__(256) void k_bscan(const int* __restrict__ bucketHist,
                                               int* __restrict__ bucketBase,
                                               int* __restrict__ bucketCursor){
  __shared__ int wt[4];
  int t = threadIdx.x, lane = t & 63, w = t >> 6;
  int v = bucketHist[t];
  int incl = v;
  #pragma unroll
  for (int o = 1; o < 64; o <<= 1){
    int x = __shfl_up(incl, o, 64);
    if (lane >= o) incl += x;
  }
  if (lane == 63) wt[w] = incl;
  __syncthreads();
  int woff = 0;
  for (int i = 0; i < w; ++i) woff += wt[i];
  int ex = woff + incl - v;
  bucketBase[t] = ex;
  bucketCursor[t] = ex;
}

// LDS-staged bucket scatter: stage 4096 edges grouped by bucket, reserve one
// global range per non-empty bucket, stream runs out contiguously.
__global__ __launch_bounds__(256) void k_bucket(const int* __restrict__ src,
                                                const int* __restrict__ dst,
                                                int* __restrict__ bucketCursor,
                                                int2* __restrict__ tmp, int E){
  __shared__ int h[256], ls[256], cur[256], gb[256];
  __shared__ int wt[4];
  __shared__ int2 staged[4096];
  __shared__ unsigned char bos[4096];
  int t = threadIdx.x, lane = t & 63, w = t >> 6;
  int base = blockIdx.x*4096;
  int2 ed[16]; int bk[16];
  h[t] = 0;
  __syncthreads();
  #pragma unroll
  for (int k = 0; k < 16; ++k){
    int e = base + k*256 + t;
    if (e < E){
      int s = src[e], d = dst[e];
      ed[k] = make_int2(s, d);
      bk[k] = d >> 8;
      atomicAdd(&h[bk[k]], 1);
    } else bk[k] = -1;
  }
  __syncthreads();
  // exclusive scan h -> ls
  int v = h[t];
  int incl = v;
  #pragma unroll
  for (int o = 1; o < 64; o <<= 1){
    int x = __shfl_up(incl, o, 64);
    if (lane >= o) incl += x;
  }
  if (lane == 63) wt[w] = incl;
  __syncthreads();
  int woff = 0;
  for (int i = 0; i < w; ++i) woff += wt[i];
  ls[t] = woff + incl - v;
  cur[t] = ls[t];
  if (v > 0) gb[t] = atomicAdd(&bucketCursor[t], v);
  __syncthreads();
  #pragma unroll
  for (int k = 0; k < 16; ++k){
    if (bk[k] >= 0){
      int lp = atomicAdd(&cur[bk[k]], 1);
      staged[lp] = ed[k];
      bos[lp] = (unsigned char)bk[k];
    }
  }
  __syncthreads();
  int nvalid = min(4096, E - base);
  #pragma unroll
  for (int k = 0; k < 16; ++k){
    int i = k*256 + t;
    if (i < nvalid){
      int b = bos[i];
      tmp[gb[b] + (i - ls[b])] = staged[i];
    }
  }
}

// one block per bucket: group by exact dst, emit rowptr/dis/csrc
__global__ __launch_bounds__(256) void k_csr(const int2* __restrict__ tmp,
                                             const int* __restrict__ bucketHist,
                                             const int* __restrict__ bucketBase,
                                             int* __restrict__ rowptr,
                                             float* __restrict__ dis,
                                             int* __restrict__ csrc, int N){
  __shared__ int h[256], ls[256], cur[256];
  __shared__ int wt[4];
  __shared__ int stagedSrc[6144];            // cap >> max bucket size (~4350)
  int b = blockIdx.x, t = threadIdx.x, lane = t & 63, w = t >> 6;
  int ebase = bucketBase[b];
  int cnt = bucketHist[b];
  int node0 = b << 8;
  h[t] = 0;
  __syncthreads();
  for (int i = t; i < cnt; i += 256){
    int2 e = tmp[ebase + i];
    atomicAdd(&h[e.y - node0], 1);
  }
  __syncthreads();
  int v = h[t];
  int incl = v;
  #pragma unroll
  for (int o = 1; o < 64; o <<= 1){
    int x = __shfl_up(incl, o, 64);
    if (lane >= o) incl += x;
  }
  if (lane == 63) wt[w] = incl;
  __syncthreads();
  int woff = 0;
  for (int i = 0; i < w; ++i) woff += wt[i];
  int ex = woff + incl - v;
  ls[t] = ex; cur[t] = ex;
  int d = node0 + t;
  if (d < N){
    rowptr[d+1] = ebase + ex + v;
    dis[d] = rsqrtf((float)v + 1.0f);
  }
  if (b == 0 && t == 0) rowptr[0] = 0;
  __syncthreads();
  for (int i = t; i < cnt; i += 256){
    int2 e = tmp[ebase + i];
    int lp = atomicAdd(&cur[e.y - node0], 1);
    stagedSrc[lp] = e.x;
  }
  __syncthreads();
  for (int i = t; i < cnt; i += 256)
    csrc[ebase + i] = stagedSrc[i];
}

// pack W [128,128] fp32 -> fragment-major bf16 for mfma_f32_16x16x32_bf16 B-operand
__global__ void k_prepW(const float* __restrict__ W1, const float* __restrict__ W2,
                        const float* __restrict__ W3, ushort* __restrict__ Wf){
  const float* Ws[3] = {W1, W2, W3};
  int l = blockIdx.y;
  int idx = blockIdx.x*256 + threadIdx.x;        // 0..16383
  int k = idx >> 7, n = idx & 127;
  float w = Ws[l][idx];
  int kb = k >> 5, q = (k >> 3) & 3, j = k & 7;
  int nt = n >> 4, col = n & 15;
  Wf[(size_t)l*16384 + (((size_t)(kb*8 + nt)*64 + q*16 + col)*8 + j)] = f2bf(w);
}

// ------------------- GEMM: bf16 MFMA, fused BN-affine+ReLU on A, dis-scale on out ----
// MODE 0: A fp32 (= x), plain convert. MODE 1: A bf16 (= AGG), affine+relu in fp32.
template<int MODE>
__global__ __launch_bounds__(256) void k_gemm(const void* __restrict__ Av,
                                              const ushort* __restrict__ Wf,
                                              const float* __restrict__ sums,
                                              const float* __restrict__ g,
                                              const float* __restrict__ be,
                                              const float* __restrict__ dis,
                                              ushort* __restrict__ O, int n, float invN){
  __shared__ float aL[HD], bL[HD];
  int tid = threadIdx.x;
  if (MODE){
    if (tid < HD){
      float m = sums[tid]*invN;
      float var = fmaxf(sums[HD+tid]*invN - m*m, 0.f);
      float Ac = g[tid]*rsqrtf(var + EPS);
      aL[tid] = Ac; bL[tid] = be[tid] - m*Ac;
    }
    __syncthreads();
  }
  int lane = tid & 63, wave = tid >> 6;
  int quad = lane >> 4, r16 = lane & 15;
  int row = blockIdx.x*64 + wave*16 + r16;
  int rowc = min(row, n-1);
  floatx4 acc[8] = {};
  #pragma unroll
  for (int kb = 0; kb < 4; ++kb){
    int k0 = kb*32 + quad*8;
    short8 af;
    if (MODE){
      const ushort* Arow = (const ushort*)Av + (size_t)rowc*HD;
      short8 raw = *(const short8*)(Arow + k0);
      #pragma unroll
      for (int jj = 0; jj < 8; ++jj){
        float f = bf2f((ushort)raw[jj]);
        f = fmaxf(f*aL[k0+jj] + bL[k0+jj], 0.f);
        af[jj] = (short)f2bf(f);
      }
    } else {
      const float* Arow = (const float*)Av + (size_t)rowc*HD;
      float4 x0 = *(const float4*)(Arow + k0);
      float4 x1 = *(const float4*)(Arow + k0 + 4);
      af[0] = (short)f2bf(x0.x); af[1] = (short)f2bf(x0.y);
      af[2] = (short)f2bf(x0.z); af[3] = (short)f2bf(x0.w);
      af[4] = (short)f2bf(x1.x); af[5] = (short)f2bf(x1.y);
      af[6] = (short)f2bf(x1.z); af[7] = (short)f2bf(x1.w);
    }
    const ushort* wp = Wf + ((size_t)(kb*8)*64 + lane)*8;
    #pragma unroll
    for (int nt = 0; nt < 8; ++nt){
      short8 bf = *(const short8*)(wp + (size_t)nt*64*8);
      acc[nt] = __builtin_amdgcn_mfma_f32_16x16x32_bf16(af, bf, acc[nt], 0, 0, 0);
    }
  }
  int rbase = blockIdx.x*64 + wave*16 + quad*4;
  float ds[4];
  #pragma unroll
  for (int r = 0; r < 4; ++r) ds[r] = dis[min(rbase + r, n-1)];
  #pragma unroll
  for (int nt = 0; nt < 8; ++nt){
    #pragma unroll
    for (int r = 0; r < 4; ++r){
      int rr = rbase + r;
      if (rr < n) O[(size_t)rr*HD + nt*16 + r16] = f2bf(acc[nt][r]*ds[r]);
    }
  }
}

// ------------------- edge aggregation + fused BN-stats partials -------------------
__global__ __launch_bounds__(256) void k_gather(const ushort* __restrict__ hw,
                                                const int* __restrict__ rowptr,
                                                const int* __restrict__ csrc,
                                                const float* __restrict__ dis,
                                                ushort* __restrict__ agg,
                                                float* __restrict__ scratch,
                                                float* __restrict__ sums, int N){
  __shared__ float2 sm[4][HD];
  if (blockIdx.x == 0) sums[threadIdx.x] = 0.f;   // zero before k_reduce's atomics
  int grp = threadIdx.x >> 4, j = threadIdx.x & 15;
  int wave = threadIdx.x >> 6, lane = threadIdx.x & 63;
  int i = blockIdx.x*16 + grp;
  bool valid = (i < N);
  int ic = valid ? i : N-1;
  uint4 q = ((const uint4*)(hw + (size_t)ic*HD))[j];
  float a[8];
  a[0] = bflo(q.x); a[1] = bfhi(q.x);
  a[2] = bflo(q.y); a[3] = bfhi(q.y);
  a[4] = bflo(q.z); a[5] = bfhi(q.z);
  a[6] = bflo(q.w); a[7] = bfhi(q.w);
  int e = rowptr[ic], e1 = rowptr[ic+1];
  #define ADD8(Q) \
    a[0] += bflo(Q.x); a[1] += bfhi(Q.x); \
    a[2] += bflo(Q.y); a[3] += bfhi(Q.y); \
    a[4] += bflo(Q.z); a[5] += bfhi(Q.z); \
    a[6] += bflo(Q.w); a[7] += bfhi(Q.w);
  while (e < e1 && (e & 3)){
    uint4 qq = ((const uint4*)(hw + (size_t)csrc[e]*HD))[j];
    ADD8(qq);
    e++;
  }
  int4 c0, c1;
  if (e + 8 <= e1){
    c0 = *(const int4*)&csrc[e];
    c1 = *(const int4*)&csrc[e+4];
  }
  while (e + 8 <= e1){
    int en = e + 8;
    int4 n0, n1;
    if (en + 8 <= e1){
      n0 = *(const int4*)&csrc[en];
      n1 = *(const int4*)&csrc[en+4];
    }
    uint4 q0 = ((const uint4*)(hw + (size_t)c0.x*HD))[j];
    uint4 q1 = ((const uint4*)(hw + (size_t)c0.y*HD))[j];
    uint4 q2 = ((const uint4*)(hw + (size_t)c0.z*HD))[j];
    uint4 q3 = ((const uint4*)(hw + (size_t)c0.w*HD))[j];
    uint4 q4 = ((const uint4*)(hw + (size_t)c1.x*HD))[j];
    uint4 q5 = ((const uint4*)(hw + (size_t)c1.y*HD))[j];
    uint4 q6 = ((const uint4*)(hw + (size_t)c1.z*HD))[j];
    uint4 q7 = ((const uint4*)(hw + (size_t)c1.w*HD))[j];
    ADD8(q0); ADD8(q1); ADD8(q2); ADD8(q3);
    ADD8(q4); ADD8(q5); ADD8(q6); ADD8(q7);
    c0 = n0; c1 = n1; e = en;
  }
  if (e + 4 <= e1){
    int4 tt = *(const int4*)&csrc[e];
    uint4 q0 = ((const uint4*)(hw + (size_t)tt.x*HD))[j];
    uint4 q1 = ((const uint4*)(hw + (size_t)tt.y*HD))[j];
    uint4 q2 = ((const uint4*)(hw + (size_t)tt.z*HD))[j];
    uint4 q3 = ((const uint4*)(hw + (size_t)tt.w*HD))[j];
    ADD8(q0); ADD8(q1); ADD8(q2); ADD8(q3);
    e += 4;
  }
  for (; e < e1; ++e){
    uint4 qq = ((const uint4*)(hw + (size_t)csrc[e]*HD))[j];
    ADD8(qq);
  }
  #undef ADD8
  float sc = dis[ic];
  #pragma unroll
  for (int k = 0; k < 8; ++k) a[k] *= sc;
  if (valid){
    uint4 o;
    o.x = (unsigned)f2bf(a[0]) | ((unsigned)f2bf(a[1]) << 16);
    o.y = (unsigned)f2bf(a[2]) | ((unsigned)f2bf(a[3]) << 16);
    o.z = (unsigned)f2bf(a[4]) | ((unsigned)f2bf(a[5]) << 16);
    o.w = (unsigned)f2bf(a[6]) | ((unsigned)f2bf(a[7]) << 16);
    ((uint4*)(agg + (size_t)i*HD))[j] = o;
  }
  float z = valid ? 1.f : 0.f;
  #pragma unroll
  for (int k = 0; k < 8; ++k){
    float s = a[k]*z, qq = a[k]*a[k]*z;
    s  += __shfl_xor(s, 16);  s  += __shfl_xor(s, 32);
    qq += __shfl_xor(qq, 16); qq += __shfl_xor(qq, 32);
    if (lane < 16) sm[wave][lane*8 + k] = make_float2(s, qq);
  }
  __syncthreads();
  int t = threadIdx.x;
  if (t < HD){
    float2 r0 = sm[0][t], r1 = sm[1][t], r2 = sm[2][t], r3 = sm[3][t];
    scratch[(size_t)blockIdx.x*256 + t]      = r0.x + r1.x + r2.x + r3.x;
    scratch[(size_t)blockIdx.x*256 + HD + t] = r0.y + r1.y + r2.y + r3.y;
  }
}

// coalesced second-stage reduction
__global__ __launch_bounds__(256) void k_reduce(const float* __restrict__ scratch,
                                                float* __restrict__ sums, int R){
  int t = threadIdx.x;
  float acc = 0.f;
  for (int r = blockIdx.x; r < R; r += gridDim.x)
    acc += scratch[(size_t)r*256 + t];
  atomicAdd(&sums[t], acc);
}

// ------------------- mean pool (fused layer-3 BN+ReLU, fused counts) -------------------

__global__ __launch_bounds__(128) void k_pool(const ushort* __restrict__ h,
                                              const int* __restrict__ batch,
                                              const float* __restrict__ sums,
                                              const float* __restrict__ g,
                                              const float* __restrict__ be,
                                              float* __restrict__ pooled,
                                              float* __restrict__ cntf, int N, float invN){
  int c = threadIdx.x;
  float m = sums[c]*invN;
  float var = fmaxf(sums[HD+c]*invN - m*m, 0.f);
  float a = g[c]*rsqrtf(var + EPS);
  float b = be[c] - m*a;
  int start = blockIdx.x * 32;
  if (start >= N) return;
  int end = min(start + 32, N);
  int cur = batch[start];
  float acc = 0.f; int run = 0;
  for (int i = start; i < end; ++i){
    int bb = batch[i];
    if (bb != cur){
      atomicAdd(&pooled[(size_t)cur*HD + c], acc);
      if (c == 0) atomicAdd(&cntf[cur], (float)run);
      acc = 0.f; run = 0; cur = bb;
    }
    acc += fmaxf(bf2f(h[(size_t)i*HD + c])*a + b, 0.f);
    run++;
  }
  atomicAdd(&pooled[(size_t)cur*HD + c], acc);
  if (c == 0) atomicAdd(&cntf[cur], (float)run);
}

// ------------------- FC head -------------------

__global__ __launch_bounds__(64) void k_fc1(const float* __restrict__ pooled,
                                            const float* __restrict__ cntf,
                                            const float* __restrict__ W,
                                            const float* __restrict__ b,
                                            float* __restrict__ z,
                                            float* __restrict__ sums2, int G){
  int g = blockIdx.x, j = threadIdx.x;
  if (g == 0){ sums2[j] = 0.f; sums2[FCD + j] = 0.f; }
  float inv = 1.0f / fmaxf(cntf[g], 1.0f);
  float acc = 0.f;
  for (int k = 0; k < HD; ++k)
    acc += pooled[(size_t)g*HD + k] * W[k*FCD + j];
  z[(size_t)g*FCD + j] = acc * inv + b[j];
}

__global__ __launch_bounds__(64) void k_stats2(const float* __restrict__ z,
                                               float* __restrict__ sums2, int G){
  int c = threadIdx.x;
  float s = 0.f, q = 0.f;
  for (int i = blockIdx.x; i < G; i += gridDim.x){
    float v = z[(size_t)i*FCD + c]; s += v; q += v*v;
  }
  atomicAdd(&sums2[c], s);
  atomicAdd(&sums2[FCD + c], q);
}

__global__ __launch_bounds__(64) void k_final(const float* __restrict__ z,
                                              const float* __restrict__ sums2,
                                              const float* __restrict__ g,
                                              const float* __restrict__ be,
                                              const float* __restrict__ w2,
                                              const float* __restrict__ b2,
                                              float* __restrict__ out, int G, float invG){
  int gg = blockIdx.x, c = threadIdx.x;
  float m = sums2[c]*invG;
  float var = fmaxf(sums2[FCD+c]*invG - m*m, 0.f);
  float A = g[c]*rsqrtf(var + EPS);
  float B = be[c] - m*A;
  float v = fmaxf(z[(size_t)gg*FCD + c]*A + B, 0.f) * w2[c];
  #pragma unroll
  for (int o = 32; o > 0; o >>= 1) v += __shfl_down(v, o, 64);
  if (c == 0) out[gg] = v + b2[0];
}

// ------------------- launch -------------------

extern "C" void kernel_launch(void* const* d_in, const int* in_sizes, int n_in,
                              void* d_out, int out_size, void* d_ws, size_t ws_size,
                              hipStream_t stream){
  const float* x    = (const float*)d_in[0];
  const int*   ei   = (const int*)d_in[1];
  const int*   batch= (const int*)d_in[2];
  const float* W1 = (const float*)d_in[3];
  const float* g1 = (const float*)d_in[5];
  const float* be1= (const float*)d_in[6];
  const float* W2 = (const float*)d_in[7];
  const float* g2 = (const float*)d_in[9];
  const float* be2= (const float*)d_in[10];
  const float* W3 = (const float*)d_in[11];
  const float* g3 = (const float*)d_in[13];
  const float* be3= (const float*)d_in[14];
  const float* fcW1 = (const float*)d_in[15];
  const float* fcb1 = (const float*)d_in[16];
  const float* fcg1 = (const float*)d_in[17];
  const float* fcbe1= (const float*)d_in[18];
  const float* fcW2 = (const float*)d_in[19];
  const float* fcb2 = (const float*)d_in[20];
  float* out = (float*)d_out;

  const int N = in_sizes[0] / HD;      // 50000
  const int E = in_sizes[1] / 2;       // 800000
  const int G = out_size;              // 500

  const int* esrc = ei;
  const int* edst = ei + E;

  char* p = (char*)d_ws;
  auto alloc = [&](size_t bytes)->void*{
    void* r = (void*)p; p += (bytes + 255) & ~(size_t)255; return r;
  };
  int gatherBlocks = (N + 15)/16;
  int nEB = (E + 4095)/4096;           // 196 edge blocks
  int NB  = (N + 255)/256;             // 196 node buckets (<=256 required)
  int*    bucketHist  = (int*) alloc(256*4);
  int*    bucketBase  = (int*) alloc(256*4);
  int*    bucketCursor= (int*) alloc(256*4);
  int2*   tmp    = (int2*)  alloc((size_t)E*8);
  int*    rowptr = (int*)   alloc((size_t)(N+1)*4);
  int*    csrc   = (int*)   alloc((size_t)E*4);
  float*  dis    = (float*) alloc((size_t)N*4);
  ushort* HWb    = (ushort*)alloc((size_t)N*HD*2);
  ushort* AGG    = (ushort*)alloc((size_t)N*HD*2);
  ushort* Wf     = (ushort*)alloc((size_t)3*HD*HD*2);
  float*  sums   = (float*) alloc(2*HD*4);
  float*  scratch= (float*) alloc((size_t)gatherBlocks*256*4);
  float*  pooled = (float*) alloc(((size_t)G*HD + G)*4);
  float*  cntf   = pooled + (size_t)G*HD;
  float*  zbuf   = (float*) alloc((size_t)G*FCD*4);
  float*  sums2  = (float*) alloc(2*FCD*4);

  float invN = 1.0f/(float)N, invG = 1.0f/(float)G;

  // CSR build (bucket sort)
  hipMemsetAsync(bucketHist, 0, 256*4, stream);
  k_hist  <<<nEB, 256, 0, stream>>>(edst, bucketHist, E);
  k_bscan <<<1, 256, 0, stream>>>(bucketHist, bucketBase, bucketCursor);
  k_bucket<<<nEB, 256, 0, stream>>>(esrc, edst, bucketCursor, tmp, E);
  k_csr   <<<NB, 256, 0, stream>>>(tmp, bucketHist, bucketBase, rowptr, dis, csrc, N);
  k_prepW <<<dim3(64,3), 256, 0, stream>>>(W1, W2, W3, Wf);

  int gemmBlocks = (N + 63)/64;

  // layer 1
  k_gemm<0> <<<gemmBlocks, 256, 0, stream>>>(x,   Wf,         nullptr, nullptr, nullptr, dis, HWb, N, invN);
  k_gather  <<<gatherBlocks, 256, 0, stream>>>(HWb, rowptr, csrc, dis, AGG, scratch, sums, N);
  k_reduce  <<<64, 256, 0, stream>>>(scratch, sums, gatherBlocks);
  // layer 2 (BN1+ReLU fused into A-load)
  k_gemm<1> <<<gemmBlocks, 256, 0, stream>>>(AGG, Wf + 16384, sums, g1, be1, dis, HWb, N, invN);
  k_gather  <<<gatherBlocks, 256, 0, stream>>>(HWb, rowptr, csrc, dis, AGG, scratch, sums, N);
  k_reduce  <<<64, 256, 0, stream>>>(scratch, sums, gatherBlocks);
  // layer 3 (BN2+ReLU fused into A-load)
  k_gemm<1> <<<gemmBlocks, 256, 0, stream>>>(AGG, Wf + 32768, sums, g2, be2, dis, HWb, N, invN);
  k_gather  <<<gatherBlocks, 256, 0, stream>>>(HWb, rowptr, csrc, dis, AGG, scratch, sums, N);
  k_reduce  <<<64, 256, 0, stream>>>(scratch, sums, gatherBlocks);

  // pool (BN3+ReLU fused) + head
  hipMemsetAsync(pooled, 0, ((size_t)G*HD + G)*4, stream);
  k_pool  <<<(N+31)/32, 128, 0, stream>>>(AGG, batch, sums, g3, be3, pooled, cntf, N, invN);
  k_fc1   <<<G, FCD, 0, stream>>>(pooled, cntf, fcW1, fcb1, zbuf, sums2, G);
  k_stats2<<<64, FCD, 0, stream>>>(zbuf, sums2, G);
  k_final <<<G, FCD, 0, stream>>>(zbuf, sums2, fcg1, fcbe1, fcW2, fcb2, out, G, invG);
}